// Round 1
// baseline (180.561 us; speedup 1.0000x reference)
//
#include <hip/hip_runtime.h>
#include <hip/hip_bf16.h>
#include <math.h>

#define B_  64
#define N_  8192
#define D_  256
#define K_  16
#define EPS_ 1e-8f

// ws layout (float units)
static const size_t SIM_OFF = 0;                        // B_*N_          = 524288
static const size_t QKV_OFF = 524288;                   // B_*3*K_*D_     = 786432
static const size_t WT_OFF  = 524288 + 786432;          // 256*768        = 196608
static const size_t WOT_OFF = WT_OFF + 196608;          // 256*256        = 65536
static const size_t TKS_OFF = WOT_OFF + 65536;          // B_*K_          = 1024
static const size_t QN_OFF  = TKS_OFF + 1024;           // B_             = 64
static const size_t TKI_OFF = QN_OFF + 64;              // B_*K_ ints     = 1024

// out[idx] = in[r*cols_in + d]  where idx = d*rows_in + r  (out is [cols_in][rows_in])
__global__ void transpose_kernel(const float* __restrict__ in, float* __restrict__ out,
                                 int rows_in, int cols_in) {
    int idx = blockIdx.x * blockDim.x + threadIdx.x;
    if (idx >= rows_in * cols_in) return;
    int d = idx / rows_in;
    int r = idx - d * rows_in;
    out[idx] = in[r * cols_in + d];
}

__global__ void qnorm_kernel(const float* __restrict__ q, float* __restrict__ qn) {
    int wid  = (blockIdx.x * blockDim.x + threadIdx.x) >> 6;
    int lane = threadIdx.x & 63;
    if (wid >= B_) return;
    float4 v = ((const float4*)(q + (size_t)wid * D_))[lane];
    float sq = v.x*v.x + v.y*v.y + v.z*v.z + v.w*v.w;
    for (int off = 32; off; off >>= 1) sq += __shfl_xor(sq, off);
    if (lane == 0) qn[wid] = sqrtf(sq);
}

__global__ void __launch_bounds__(256)
sim_kernel(const float* __restrict__ q, const float* __restrict__ km,
           const int* __restrict__ iter, const float* __restrict__ qn,
           float* __restrict__ sim) {
    int lane   = threadIdx.x & 63;
    int wid    = (blockIdx.x * blockDim.x + threadIdx.x) >> 6;
    int nwaves = (gridDim.x * blockDim.x) >> 6;
    for (int row = wid; row < B_ * N_; row += nwaves) {
        int b = row >> 13;          // row / N_
        int n = row & (N_ - 1);
        float s = 0.f;
        if (n <= iter[b]) {
            float4 kv = ((const float4*)(km + (size_t)row * D_))[lane];
            float4 qv = ((const float4*)(q  + (size_t)b   * D_))[lane];
            float dot = kv.x*qv.x + kv.y*qv.y + kv.z*qv.z + kv.w*qv.w;
            float sq  = kv.x*kv.x + kv.y*kv.y + kv.z*kv.z + kv.w*kv.w;
            for (int off = 32; off; off >>= 1) {
                dot += __shfl_xor(dot, off);
                sq  += __shfl_xor(sq,  off);
            }
            s = dot / fmaxf(sqrtf(sq) * qn[b], EPS_);
        }
        if (lane == 0) sim[row] = s;
    }
}

__global__ void __launch_bounds__(256)
topk_kernel(const float* __restrict__ sim, float* __restrict__ tks, int* __restrict__ tki) {
    int b = blockIdx.x, tid = threadIdx.x;
    __shared__ float sv[N_];
    __shared__ float rv[256];
    __shared__ int   ri[256];
    for (int i = tid; i < N_; i += 256) sv[i] = sim[(size_t)b * N_ + i];
    __syncthreads();
    for (int sel = 0; sel < K_; sel++) {
        float best = -3.4e38f; int bi = N_;
        for (int i = tid; i < N_; i += 256) {
            float v = sv[i];
            if (v > best) { best = v; bi = i; }   // ascending i -> lowest idx on ties
        }
        rv[tid] = best; ri[tid] = bi;
        __syncthreads();
        for (int s = 128; s > 0; s >>= 1) {
            if (tid < s) {
                if (rv[tid+s] > rv[tid] || (rv[tid+s] == rv[tid] && ri[tid+s] < ri[tid])) {
                    rv[tid] = rv[tid+s]; ri[tid] = ri[tid+s];
                }
            }
            __syncthreads();
        }
        if (tid == 0) {
            tks[b*K_ + sel] = rv[0];
            tki[b*K_ + sel] = ri[0];
            sv[ri[0]] = -3.4e38f;
        }
        __syncthreads();
    }
}

// one block per (b, which): which=0 q, 1 k, 2 v.  WT is in_proj_w^T: [256][768].
__global__ void __launch_bounds__(256)
qkv_kernel(const float* __restrict__ vm, const int* __restrict__ iter,
           const float* __restrict__ tks, const int* __restrict__ tki,
           const float* __restrict__ WT, const float* __restrict__ inb,
           float* __restrict__ qkv) {
    int b = blockIdx.x / 3, which = blockIdx.x % 3;
    int tid = threadIdx.x;
    int it = iter[b];
    if (it == 0) return;                 // final kernel writes zeros; qkv unused
    __shared__ float xT[D_][K_];         // xT[d][k], row = 64B aligned
    __shared__ float wv[K_];
    if (tid < K_) {
        float m = -3.4e38f;
        for (int j = 0; j < K_; j++) m = fmaxf(m, tks[b*K_ + j]);
        float ssum = 0.f;
        for (int j = 0; j < K_; j++) ssum += expf(tks[b*K_ + j] - m);
        wv[tid] = expf(tks[b*K_ + tid] - m) / ssum;
    }
    __syncthreads();
    for (int k = 0; k < K_; k++) {
        int idx = tki[b*K_ + k];
        float val = 0.f;
        if (idx <= it) val = wv[k] * vm[((size_t)b * N_ + idx) * D_ + tid];
        xT[tid][k] = val;                // masked picks gather zeros (vm masked)
    }
    __syncthreads();
    float acc[K_];
    #pragma unroll
    for (int k = 0; k < K_; k++) acc[k] = 0.f;
    const float* wt = WT + which * D_ + tid;   // coalesced column walk of W^T
    #pragma unroll 4
    for (int d = 0; d < D_; d++) {
        float w = wt[(size_t)d * 768];
        #pragma unroll
        for (int k = 0; k < K_; k++) acc[k] += xT[d][k] * w;
    }
    float bias = inb[which * D_ + tid];
    #pragma unroll
    for (int k = 0; k < K_; k++)
        qkv[(((size_t)b * 3 + which) * K_ + k) * D_ + tid] = acc[k] + bias;
}

// one block per b. WoT is out_proj_w^T [256][256].
__global__ void __launch_bounds__(256)
final_kernel(const float* __restrict__ qkv, const int* __restrict__ iter,
             const float* __restrict__ WoT, const float* __restrict__ ob,
             float* __restrict__ out) {
    int b = blockIdx.x, tid = threadIdx.x;
    int it = iter[b];
    if (it == 0) { out[(size_t)b * D_ + tid] = 0.f; return; }
    __shared__ float qs[K_][D_ + 1];
    __shared__ float ks[K_][D_ + 1];
    __shared__ float vs[K_][D_ + 1];
    __shared__ float attn[K_][K_];
    __shared__ float colsum[K_];
    __shared__ float so[D_];
    const float* base = qkv + (size_t)b * 3 * K_ * D_;
    for (int k = 0; k < K_; k++) {
        qs[k][tid] = base[(0*K_ + k) * D_ + tid];
        ks[k][tid] = base[(1*K_ + k) * D_ + tid];
        vs[k][tid] = base[(2*K_ + k) * D_ + tid];
    }
    __syncthreads();
    // scores: thread (i,j), 16x16 = 256 threads exactly
    int i = tid >> 4, j = tid & 15;
    float s = 0.f;
    for (int d = 0; d < D_; d++) s += qs[i][d] * ks[j][d];
    attn[i][j] = s * 0.0625f;            // 1/sqrt(256)
    __syncthreads();
    if (tid < K_) {                       // softmax row tid
        float m = -3.4e38f;
        for (int jj = 0; jj < K_; jj++) m = fmaxf(m, attn[tid][jj]);
        float ssum = 0.f;
        for (int jj = 0; jj < K_; jj++) ssum += expf(attn[tid][jj] - m);
        float inv = 1.f / ssum;
        for (int jj = 0; jj < K_; jj++) attn[tid][jj] = expf(attn[tid][jj] - m) * inv;
    }
    __syncthreads();
    if (tid < K_) {                       // sum over output tokens commutes: colsum
        float c = 0.f;
        for (int ii = 0; ii < K_; ii++) c += attn[ii][tid];
        colsum[tid] = c;
    }
    __syncthreads();
    float acc = 0.f;
    for (int jj = 0; jj < K_; jj++) acc += colsum[jj] * vs[jj][tid];
    so[tid] = acc;                        // Σ_k o[k][tid]
    __syncthreads();
    float o = 0.f;
    for (int e = 0; e < D_; e++) o += so[e] * WoT[e * D_ + tid];
    out[(size_t)b * D_ + tid] = o + 16.f * ob[tid];   // Σ_k bias = K*bias
}

extern "C" void kernel_launch(void* const* d_in, const int* in_sizes, int n_in,
                              void* d_out, int out_size, void* d_ws, size_t ws_size,
                              hipStream_t stream) {
    const float* q   = (const float*)d_in[0];
    const float* km  = (const float*)d_in[1];
    const float* vm  = (const float*)d_in[2];
    const int*   it  = (const int*)  d_in[3];
    const float* inw = (const float*)d_in[4];
    const float* inb = (const float*)d_in[5];
    const float* ow  = (const float*)d_in[6];
    const float* ob  = (const float*)d_in[7];
    float* out = (float*)d_out;

    float* ws  = (float*)d_ws;
    float* sim = ws + SIM_OFF;
    float* qkv = ws + QKV_OFF;
    float* WT  = ws + WT_OFF;
    float* WoT = ws + WOT_OFF;
    float* tks = ws + TKS_OFF;
    float* qn  = ws + QN_OFF;
    int*   tki = (int*)(ws + TKI_OFF);

    transpose_kernel<<<dim3(768), dim3(256), 0, stream>>>(inw, WT, 768, 256);
    transpose_kernel<<<dim3(256), dim3(256), 0, stream>>>(ow, WoT, 256, 256);
    qnorm_kernel<<<dim3(16), dim3(256), 0, stream>>>(q, qn);
    sim_kernel<<<dim3(8192), dim3(256), 0, stream>>>(q, km, it, qn, sim);
    topk_kernel<<<dim3(B_), dim3(256), 0, stream>>>(sim, tks, tki);
    qkv_kernel<<<dim3(B_ * 3), dim3(256), 0, stream>>>(vm, it, tks, tki, WT, inb, qkv);
    final_kernel<<<dim3(B_), dim3(256), 0, stream>>>(qkv, it, WoT, ob, out);
}

// Round 2
// 160.074 us; speedup vs baseline: 1.1280x; 1.1280x over previous
//
#include <hip/hip_runtime.h>
#include <hip/hip_bf16.h>
#include <math.h>

#define B_  64
#define N_  8192
#define D_  256
#define K_  16
#define NCHUNK_ 32
#define EPS_ 1e-8f
#define NEG_ -3.4e38f

// ws layout (float units), all offsets 64B-aligned
static const size_t CANDV_OFF = 0;                       // B_*NCHUNK_*K_ = 32768
static const size_t CANDI_OFF = 32768;                   // 32768 ints
static const size_t XT_OFF    = 65536;                   // B_*D_*K_ = 262144  [b][d][k]
static const size_t WT_OFF    = 65536 + 262144;          // 256*768 = 196608   [d][e]
static const size_t WOT_OFF   = WT_OFF + 196608;         // 256*256 = 65536    [d][e]
static const size_t QKV_OFF   = WOT_OFF + 65536;         // B_*3*K_*D_ = 786432

// both weight transposes in one launch
__global__ void __launch_bounds__(256)
prep_kernel(const float* __restrict__ inw, const float* __restrict__ ow,
            float* __restrict__ WT, float* __restrict__ WoT) {
    int idx = blockIdx.x * blockDim.x + threadIdx.x;
    if (idx < 768 * 256) {               // WT[d*768 + r] = inw[r*256 + d]
        int d = idx / 768, r = idx - d * 768;
        WT[idx] = inw[r * 256 + d];
    } else {
        int idx2 = idx - 768 * 256;      // WoT[d*256 + r] = ow[r*256 + d]
        if (idx2 < 256 * 256) {
            int d = idx2 >> 8, r = idx2 & 255;
            WoT[idx2] = ow[r * 256 + d];
        }
    }
}

// grid 2048: (b, chunk). Rows of chunk c: n = c + 32*l, l in [0,256).
// Computes sims (qnorm inline) and this chunk's stable top-16 candidates.
__global__ void __launch_bounds__(256)
simtopk_kernel(const float* __restrict__ q, const float* __restrict__ km,
               const int* __restrict__ iter,
               float* __restrict__ cand_v, int* __restrict__ cand_i) {
    int b = blockIdx.x >> 5;
    int chunk = blockIdx.x & (NCHUNK_ - 1);
    int tid = threadIdx.x;
    int w = tid >> 6;                     // wave 0..3
    int lane = tid & 63;
    int it = iter[b];

    __shared__ float svals[256];
    __shared__ float rv4[4];
    __shared__ int   ri4[4];

    // q row in registers; qn via butterfly (uniform, shuffles safe)
    float4 qv = ((const float4*)(q + (size_t)b * D_))[lane];
    float qq = qv.x*qv.x + qv.y*qv.y + qv.z*qv.z + qv.w*qv.w;
    for (int off = 32; off; off >>= 1) qq += __shfl_xor(qq, off);
    float qn = sqrtf(qq);

    // wave-interleaved local rows l = 4*j + w  (balances valid prefix)
    for (int j = 0; j < 64; j++) {
        int l = (j << 2) + w;
        int n = chunk + (l << 5);
        float s = 0.f;
        if (n <= it) {                    // wave-uniform branch
            float4 kv = ((const float4*)(km + ((size_t)b * N_ + n) * D_))[lane];
            float dot = kv.x*qv.x + kv.y*qv.y + kv.z*qv.z + kv.w*qv.w;
            float sq  = kv.x*kv.x + kv.y*kv.y + kv.z*kv.z + kv.w*kv.w;
            for (int off = 32; off; off >>= 1) {
                dot += __shfl_xor(dot, off);
                sq  += __shfl_xor(sq,  off);
            }
            s = dot / fmaxf(sqrtf(sq) * qn, EPS_);
        }
        if (lane == 0) svals[l] = s;
    }
    __syncthreads();

    // register-resident iterative top-16 (value desc, index asc)
    float v = svals[tid];
    int   idx = chunk + (tid << 5);
    for (int sel = 0; sel < K_; sel++) {
        float bv = v; int bi = idx;
        for (int off = 32; off; off >>= 1) {
            float ov = __shfl_xor(bv, off);
            int   oi = __shfl_xor(bi, off);
            if (ov > bv || (ov == bv && oi < bi)) { bv = ov; bi = oi; }
        }
        if (lane == 0) { rv4[w] = bv; ri4[w] = bi; }
        __syncthreads();
        float wv0 = rv4[0]; int wi0 = ri4[0];
        #pragma unroll
        for (int w2 = 1; w2 < 4; w2++) {
            float ov = rv4[w2]; int oi = ri4[w2];
            if (ov > wv0 || (ov == wv0 && oi < wi0)) { wv0 = ov; wi0 = oi; }
        }
        if (idx == wi0) v = NEG_;         // idx unique per thread -> unique claim
        if (tid == 0) {
            cand_v[(size_t)blockIdx.x * K_ + sel] = wv0;
            cand_i[(size_t)blockIdx.x * K_ + sel] = wi0;
        }
        __syncthreads();                  // rv4 reuse fence
    }
}

// 64 blocks: merge 512 candidates -> top-16, softmax, masked gather into xT[b][d][k]
__global__ void __launch_bounds__(256)
merge_gather_kernel(const float* __restrict__ cand_v, const int* __restrict__ cand_i,
                    const float* __restrict__ vm, const int* __restrict__ iter,
                    float* __restrict__ xT) {
    int b = blockIdx.x, tid = threadIdx.x;
    int w = tid >> 6, lane = tid & 63;
    int it = iter[b];
    float v0 = cand_v[(size_t)b * 512 + tid];
    float v1 = cand_v[(size_t)b * 512 + 256 + tid];
    int   i0 = cand_i[(size_t)b * 512 + tid];
    int   i1 = cand_i[(size_t)b * 512 + 256 + tid];
    __shared__ float selv[K_];
    __shared__ int   seli[K_];
    __shared__ float w16[K_];
    __shared__ float rv4[4];
    __shared__ int   ri4[4];
    for (int sel = 0; sel < K_; sel++) {
        float bv; int bi;
        if (v1 > v0 || (v1 == v0 && i1 < i0)) { bv = v1; bi = i1; }
        else                                  { bv = v0; bi = i0; }
        for (int off = 32; off; off >>= 1) {
            float ov = __shfl_xor(bv, off);
            int   oi = __shfl_xor(bi, off);
            if (ov > bv || (ov == bv && oi < bi)) { bv = ov; bi = oi; }
        }
        if (lane == 0) { rv4[w] = bv; ri4[w] = bi; }
        __syncthreads();
        float wv0 = rv4[0]; int wi0 = ri4[0];
        #pragma unroll
        for (int w2 = 1; w2 < 4; w2++) {
            float ov = rv4[w2]; int oi = ri4[w2];
            if (ov > wv0 || (ov == wv0 && oi < wi0)) { wv0 = ov; wi0 = oi; }
        }
        if (i0 == wi0) v0 = NEG_;         // indices globally unique
        if (i1 == wi0) v1 = NEG_;
        if (tid == 0) { selv[sel] = wv0; seli[sel] = wi0; }
        __syncthreads();
    }
    if (tid < K_) {                       // softmax weights (redundant per thread)
        float m = NEG_;
        for (int jj = 0; jj < K_; jj++) m = fmaxf(m, selv[jj]);
        float ssum = 0.f;
        for (int jj = 0; jj < K_; jj++) ssum += expf(selv[jj] - m);
        w16[tid] = expf(selv[tid] - m) / ssum;
    }
    __syncthreads();
    float* xb = xT + (size_t)b * (D_ * K_);
    #pragma unroll
    for (int k = 0; k < K_; k++) {
        int row = seli[k];
        float val = 0.f;
        if (row <= it) val = w16[k] * vm[((size_t)b * N_ + row) * D_ + tid];
        xb[tid * K_ + k] = val;           // [d][k], k-contiguous 64B rows
    }
}

// 192 blocks (b, which): y[e,k] = sum_d xT[b][d][k] * W[e][d] + bias[e]
__global__ void __launch_bounds__(256)
qkv_kernel(const float* __restrict__ xT, const float* __restrict__ WT,
           const float* __restrict__ inb, float* __restrict__ qkv) {
    int b = blockIdx.x / 3, which = blockIdx.x % 3;
    int tid = threadIdx.x;
    float acc[K_];
    #pragma unroll
    for (int k = 0; k < K_; k++) acc[k] = 0.f;
    const float* xb = xT + (size_t)b * (D_ * K_);
    const float* wt = WT + which * 256 + tid;
    #pragma unroll 4
    for (int d = 0; d < D_; d++) {
        float wgt = wt[(size_t)d * 768];
        float4 x0 = ((const float4*)(xb + d * K_))[0];   // uniform addr -> scalar loads
        float4 x1 = ((const float4*)(xb + d * K_))[1];
        float4 x2 = ((const float4*)(xb + d * K_))[2];
        float4 x3 = ((const float4*)(xb + d * K_))[3];
        acc[0]  += x0.x * wgt; acc[1]  += x0.y * wgt; acc[2]  += x0.z * wgt; acc[3]  += x0.w * wgt;
        acc[4]  += x1.x * wgt; acc[5]  += x1.y * wgt; acc[6]  += x1.z * wgt; acc[7]  += x1.w * wgt;
        acc[8]  += x2.x * wgt; acc[9]  += x2.y * wgt; acc[10] += x2.z * wgt; acc[11] += x2.w * wgt;
        acc[12] += x3.x * wgt; acc[13] += x3.y * wgt; acc[14] += x3.z * wgt; acc[15] += x3.w * wgt;
    }
    float bias = inb[which * 256 + tid];
    #pragma unroll
    for (int k = 0; k < K_; k++)
        qkv[(((size_t)b * 3 + which) * K_ + k) * D_ + tid] = acc[k] + bias;
}

// 64 blocks: attention (sum over tokens commutes through colsum) + out-proj
__global__ void __launch_bounds__(256)
final_kernel(const float* __restrict__ qkv, const int* __restrict__ iter,
             const float* __restrict__ WoT, const float* __restrict__ ob,
             float* __restrict__ out) {
    int b = blockIdx.x, tid = threadIdx.x;
    int it = iter[b];
    if (it == 0) { out[(size_t)b * D_ + tid] = 0.f; return; }
    __shared__ float qs[K_][D_ + 1];
    __shared__ float ks[K_][D_ + 1];
    __shared__ float vs[K_][D_ + 1];
    __shared__ float attn[K_][K_];
    __shared__ float colsum[K_];
    __shared__ float so[D_];
    const float* base = qkv + (size_t)b * 3 * K_ * D_;
    #pragma unroll
    for (int k = 0; k < K_; k++) {
        qs[k][tid] = base[(0 * K_ + k) * D_ + tid];
        ks[k][tid] = base[(1 * K_ + k) * D_ + tid];
        vs[k][tid] = base[(2 * K_ + k) * D_ + tid];
    }
    __syncthreads();
    int i = tid >> 4, j = tid & 15;
    float s = 0.f;
    for (int d = 0; d < D_; d++) s += qs[i][d] * ks[j][d];
    attn[i][j] = s * 0.0625f;             // 1/sqrt(256)
    __syncthreads();
    if (tid < K_) {
        float m = NEG_;
        for (int jj = 0; jj < K_; jj++) m = fmaxf(m, attn[tid][jj]);
        float ssum = 0.f;
        for (int jj = 0; jj < K_; jj++) ssum += expf(attn[tid][jj] - m);
        float inv = 1.f / ssum;
        for (int jj = 0; jj < K_; jj++) attn[tid][jj] = expf(attn[tid][jj] - m) * inv;
    }
    __syncthreads();
    if (tid < K_) {
        float c = 0.f;
        for (int ii = 0; ii < K_; ii++) c += attn[ii][tid];
        colsum[tid] = c;
    }
    __syncthreads();
    float acc = 0.f;
    #pragma unroll
    for (int jj = 0; jj < K_; jj++) acc += colsum[jj] * vs[jj][tid];
    so[tid] = acc;
    __syncthreads();
    float o = 0.f;
    for (int e = 0; e < D_; e++) o += so[e] * WoT[e * D_ + tid];
    out[(size_t)b * D_ + tid] = o + 16.f * ob[tid];
}

extern "C" void kernel_launch(void* const* d_in, const int* in_sizes, int n_in,
                              void* d_out, int out_size, void* d_ws, size_t ws_size,
                              hipStream_t stream) {
    const float* q   = (const float*)d_in[0];
    const float* km  = (const float*)d_in[1];
    const float* vm  = (const float*)d_in[2];
    const int*   it  = (const int*)  d_in[3];
    const float* inw = (const float*)d_in[4];
    const float* inb = (const float*)d_in[5];
    const float* ow  = (const float*)d_in[6];
    const float* ob  = (const float*)d_in[7];
    float* out = (float*)d_out;

    float* ws     = (float*)d_ws;
    float* cand_v = ws + CANDV_OFF;
    int*   cand_i = (int*)(ws + CANDI_OFF);
    float* xT     = ws + XT_OFF;
    float* WT     = ws + WT_OFF;
    float* WoT    = ws + WOT_OFF;
    float* qkv    = ws + QKV_OFF;

    prep_kernel<<<dim3(1024), dim3(256), 0, stream>>>(inw, ow, WT, WoT);
    simtopk_kernel<<<dim3(B_ * NCHUNK_), dim3(256), 0, stream>>>(q, km, it, cand_v, cand_i);
    merge_gather_kernel<<<dim3(B_), dim3(256), 0, stream>>>(cand_v, cand_i, vm, it, xT);
    qkv_kernel<<<dim3(B_ * 3), dim3(256), 0, stream>>>(xT, WT, inb, qkv);
    final_kernel<<<dim3(B_), dim3(256), 0, stream>>>(qkv, it, WoT, ob, out);
}

// Round 3
// 128.551 us; speedup vs baseline: 1.4046x; 1.2452x over previous
//
#include <hip/hip_runtime.h>
#include <hip/hip_bf16.h>
#include <math.h>

#define B_   64
#define N_   8192
#define D_   256
#define K_   16
#define NCH_ 32            // chunks per b, 256 rows each
#define CPB_ 2048          // candidates per b = NCH_ * 4 waves * 16
#define EPS_ 1e-8f
#define NEG_ -3.4e38f

// ws layout (float units)
static const size_t CANDV_OFF = 0;              // B_*CPB_ = 131072
static const size_t CANDI_OFF = 131072;         // 131072 ints
static const size_t QKV_OFF   = 262144;         // B_*3*K_*D_ = 786432

// ---------------------------------------------------------------------------
// A: sims + per-wave top-16 candidates.
// grid = B_*NCH_ blocks of 256. Wave w owns 64 consecutive rows
// [chunk*256 + w*64, +64). 16-lane groups: group g computes row 4t+g of
// iteration t, each lane holding 16 floats of the row (4x float4).
// ---------------------------------------------------------------------------
__global__ void __launch_bounds__(256)
simtopk_kernel(const float* __restrict__ q, const float* __restrict__ km,
               const int* __restrict__ iter,
               float* __restrict__ cand_v, int* __restrict__ cand_i) {
    int b     = blockIdx.x >> 5;
    int chunk = blockIdx.x & (NCH_ - 1);
    int tid   = threadIdx.x;
    int w     = tid >> 6;
    int lane  = tid & 63;
    int g     = lane >> 4;          // row group 0..3
    int p     = lane & 15;          // position within row
    int it    = iter[b];
    int r0    = (chunk << 8) + (w << 6);            // wave's first row
    size_t cbase = ((size_t)blockIdx.x * 4 + w) * K_;

    if (r0 > it) {   // fully masked wave: top-16 = zeros at 16 lowest indices
        if (lane < K_) { cand_v[cbase + lane] = 0.f; cand_i[cbase + lane] = r0 + lane; }
        return;
    }

    __shared__ float svals[256];    // per-wave private 64-slot sections

    // q fragment (per lane 16 floats) + ||q|| via 16-lane butterfly
    float4 q4[4];
    #pragma unroll
    for (int k = 0; k < 4; k++)
        q4[k] = *(const float4*)(q + (size_t)b * D_ + k * 64 + p * 4);
    float qq = 0.f;
    #pragma unroll
    for (int k = 0; k < 4; k++)
        qq += q4[k].x*q4[k].x + q4[k].y*q4[k].y + q4[k].z*q4[k].z + q4[k].w*q4[k].w;
    #pragma unroll
    for (int off = 8; off; off >>= 1) qq += __shfl_xor(qq, off);
    float qn = sqrtf(qq);

    for (int t = 0; t < 16; t++) {
        int r = r0 + (t << 2) + g;
        float s = 0.f;
        if (r <= it) {              // uniform within the 16-lane group
            const float* rp = km + ((size_t)b * N_ + r) * D_;
            float dot = 0.f, sq = 0.f;
            #pragma unroll
            for (int k = 0; k < 4; k++) {
                float4 kv = *(const float4*)(rp + k * 64 + p * 4);
                dot += kv.x*q4[k].x + kv.y*q4[k].y + kv.z*q4[k].z + kv.w*q4[k].w;
                sq  += kv.x*kv.x + kv.y*kv.y + kv.z*kv.z + kv.w*kv.w;
            }
            #pragma unroll
            for (int off = 8; off; off >>= 1) {   // stays within the 16-lane group
                dot += __shfl_xor(dot, off);
                sq  += __shfl_xor(sq,  off);
            }
            s = dot / fmaxf(sqrtf(sq) * qn, EPS_);
        }
        if (p == 0) svals[(w << 6) + (t << 2) + g] = s;
    }

    // per-wave top-16 of its 64 rows (value desc, index asc); same-wave LDS
    // write->read is ordered, no barrier needed
    float v  = svals[(w << 6) + lane];
    int  idx = r0 + lane;
    for (int sel = 0; sel < K_; sel++) {
        float bv = v; int bi = idx;
        #pragma unroll
        for (int off = 32; off; off >>= 1) {
            float ov = __shfl_xor(bv, off);
            int   oi = __shfl_xor(bi, off);
            if (ov > bv || (ov == bv && oi < bi)) { bv = ov; bi = oi; }
        }
        if (idx == bi) v = NEG_;    // unique index per lane -> unique claim
        if (lane == 0) { cand_v[cbase + sel] = bv; cand_i[cbase + sel] = bi; }
    }
}

// ---------------------------------------------------------------------------
// B: merge 2048 candidates -> top-16, softmax, gather vm, qkv projection.
// grid = B_*3 blocks (b, which); merge redundantly computed per which.
// y[e,k] = sum_d x[k,d] * inw[which*256+e][d] + inb  (inw rows read directly)
// ---------------------------------------------------------------------------
__global__ void __launch_bounds__(256)
merge_qkv_kernel(const float* __restrict__ cand_v, const int* __restrict__ cand_i,
                 const float* __restrict__ vm, const int* __restrict__ iter,
                 const float* __restrict__ inw, const float* __restrict__ inb,
                 float* __restrict__ qkv) {
    int b = blockIdx.x / 3, which = blockIdx.x - b * 3;
    int tid = threadIdx.x, w = tid >> 6, lane = tid & 63;
    int it = iter[b];
    if (it == 0) return;            // final kernel emits zeros; qkv unused

    float cv[8]; int ci[8];
    #pragma unroll
    for (int j = 0; j < 8; j++) {
        cv[j] = cand_v[(size_t)b * CPB_ + (j << 8) + tid];
        ci[j] = cand_i[(size_t)b * CPB_ + (j << 8) + tid];
    }

    __shared__ float rv4[4]; __shared__ int ri4[4];
    __shared__ float selv[K_]; __shared__ int seli[K_];
    __shared__ float w16[K_];
    __shared__ float xs[D_][K_];    // x^T: [d][k], 64B rows

    for (int sel = 0; sel < K_; sel++) {
        float bv = cv[0]; int bi = ci[0];
        #pragma unroll
        for (int j = 1; j < 8; j++)
            if (cv[j] > bv || (cv[j] == bv && ci[j] < bi)) { bv = cv[j]; bi = ci[j]; }
        #pragma unroll
        for (int off = 32; off; off >>= 1) {
            float ov = __shfl_xor(bv, off);
            int   oi = __shfl_xor(bi, off);
            if (ov > bv || (ov == bv && oi < bi)) { bv = ov; bi = oi; }
        }
        if (lane == 0) { rv4[w] = bv; ri4[w] = bi; }
        __syncthreads();
        float wv = rv4[0]; int wi = ri4[0];
        #pragma unroll
        for (int w2 = 1; w2 < 4; w2++)
            if (rv4[w2] > wv || (rv4[w2] == wv && ri4[w2] < wi)) { wv = rv4[w2]; wi = ri4[w2]; }
        #pragma unroll
        for (int j = 0; j < 8; j++) if (ci[j] == wi) cv[j] = NEG_;   // global-unique idx
        if (tid == 0) { selv[sel] = wv; seli[sel] = wi; }
        __syncthreads();            // rv4 reuse fence
    }

    if (tid < K_) {
        float m = NEG_;
        for (int jj = 0; jj < K_; jj++) m = fmaxf(m, selv[jj]);
        float ssum = 0.f;
        for (int jj = 0; jj < K_; jj++) ssum += expf(selv[jj] - m);
        w16[tid] = expf(selv[tid] - m) / ssum;
    }
    __syncthreads();

    #pragma unroll
    for (int k = 0; k < K_; k++) {
        int row = seli[k];
        float val = (row <= it) ? w16[k] * vm[((size_t)b * N_ + row) * D_ + tid] : 0.f;
        xs[tid][k] = val;
    }
    __syncthreads();

    float acc[K_];
    #pragma unroll
    for (int k = 0; k < K_; k++) acc[k] = 0.f;
    const float* wrow = inw + ((size_t)(which * D_ + tid)) * D_;   // contiguous row
    for (int d = 0; d < D_; d += 4) {
        float4 wv4 = *(const float4*)(wrow + d);
        float wk[4] = {wv4.x, wv4.y, wv4.z, wv4.w};
        #pragma unroll
        for (int dd = 0; dd < 4; dd++) {
            float wgt = wk[dd];
            float4 x0 = *(const float4*)(&xs[d + dd][0]);
            float4 x1 = *(const float4*)(&xs[d + dd][4]);
            float4 x2 = *(const float4*)(&xs[d + dd][8]);
            float4 x3 = *(const float4*)(&xs[d + dd][12]);
            acc[0]  += x0.x * wgt; acc[1]  += x0.y * wgt; acc[2]  += x0.z * wgt; acc[3]  += x0.w * wgt;
            acc[4]  += x1.x * wgt; acc[5]  += x1.y * wgt; acc[6]  += x1.z * wgt; acc[7]  += x1.w * wgt;
            acc[8]  += x2.x * wgt; acc[9]  += x2.y * wgt; acc[10] += x2.z * wgt; acc[11] += x2.w * wgt;
            acc[12] += x3.x * wgt; acc[13] += x3.y * wgt; acc[14] += x3.z * wgt; acc[15] += x3.w * wgt;
        }
    }
    float bias = inb[which * D_ + tid];
    #pragma unroll
    for (int k = 0; k < K_; k++)
        qkv[(((size_t)b * 3 + which) * K_ + k) * D_ + tid] = acc[k] + bias;
}

// ---------------------------------------------------------------------------
// C: attention (token-sum commutes -> colsum trick) + output projection.
// grid = B_ blocks. out[tid] = sum_e so[e]*ow[tid][e] + K_*ob[tid]
// ---------------------------------------------------------------------------
__global__ void __launch_bounds__(256)
final_kernel(const float* __restrict__ qkv, const int* __restrict__ iter,
             const float* __restrict__ ow, const float* __restrict__ ob,
             float* __restrict__ out) {
    int b = blockIdx.x, tid = threadIdx.x;
    int it = iter[b];
    if (it == 0) { out[(size_t)b * D_ + tid] = 0.f; return; }
    __shared__ float qs[K_][D_ + 1];
    __shared__ float ks[K_][D_ + 1];
    __shared__ float vs[K_][D_ + 1];
    __shared__ float attn[K_][K_];
    __shared__ float colsum[K_];
    __shared__ float so[D_];
    const float* base = qkv + (size_t)b * 3 * K_ * D_;
    #pragma unroll
    for (int k = 0; k < K_; k++) {
        qs[k][tid] = base[(0 * K_ + k) * D_ + tid];
        ks[k][tid] = base[(1 * K_ + k) * D_ + tid];
        vs[k][tid] = base[(2 * K_ + k) * D_ + tid];
    }
    __syncthreads();
    int i = tid >> 4, j = tid & 15;
    float s = 0.f;
    for (int d = 0; d < D_; d++) s += qs[i][d] * ks[j][d];
    attn[i][j] = s * 0.0625f;       // 1/sqrt(256)
    __syncthreads();
    if (tid < K_) {
        float m = NEG_;
        for (int jj = 0; jj < K_; jj++) m = fmaxf(m, attn[tid][jj]);
        float ssum = 0.f;
        for (int jj = 0; jj < K_; jj++) ssum += expf(attn[tid][jj] - m);
        float inv = 1.f / ssum;
        for (int jj = 0; jj < K_; jj++) attn[tid][jj] = expf(attn[tid][jj] - m) * inv;
    }
    __syncthreads();
    if (tid < K_) {
        float c = 0.f;
        for (int ii = 0; ii < K_; ii++) c += attn[ii][tid];
        colsum[tid] = c;
    }
    __syncthreads();
    float acc = 0.f;
    #pragma unroll
    for (int jj = 0; jj < K_; jj++) acc += colsum[jj] * vs[jj][tid];
    so[tid] = acc;
    __syncthreads();
    float o = 0.f;
    const float* orow = ow + (size_t)tid * D_;     // contiguous row of out_proj_w
    for (int e = 0; e < D_; e += 4) {
        float4 wv = *(const float4*)(orow + e);
        float4 sv = *(const float4*)(&so[e]);      // broadcast
        o += sv.x * wv.x + sv.y * wv.y + sv.z * wv.z + sv.w * wv.w;
    }
    out[(size_t)b * D_ + tid] = o + 16.f * ob[tid];
}

extern "C" void kernel_launch(void* const* d_in, const int* in_sizes, int n_in,
                              void* d_out, int out_size, void* d_ws, size_t ws_size,
                              hipStream_t stream) {
    const float* q   = (const float*)d_in[0];
    const float* km  = (const float*)d_in[1];
    const float* vm  = (const float*)d_in[2];
    const int*   it  = (const int*)  d_in[3];
    const float* inw = (const float*)d_in[4];
    const float* inb = (const float*)d_in[5];
    const float* ow  = (const float*)d_in[6];
    const float* ob  = (const float*)d_in[7];
    float* out = (float*)d_out;

    float* ws     = (float*)d_ws;
    float* cand_v = ws + CANDV_OFF;
    int*   cand_i = (int*)(ws + CANDI_OFF);
    float* qkv    = ws + QKV_OFF;

    simtopk_kernel<<<dim3(B_ * NCH_), dim3(256), 0, stream>>>(q, km, it, cand_v, cand_i);
    merge_qkv_kernel<<<dim3(B_ * 3), dim3(256), 0, stream>>>(cand_v, cand_i, vm, it, inw, inb, qkv);
    final_kernel<<<dim3(B_), dim3(256), 0, stream>>>(qkv, it, ow, ob, out);
}